// Round 1
// baseline (213.152 us; speedup 1.0000x reference)
//
#include <hip/hip_runtime.h>

#define BATCH 128
#define SEQ   1024
#define DIM   128
#define NCAP  32
#define DCAPS 16
#define KTOT  512
#define EPS_  1e-7f
#define RCH   8
#define RROWS 128

// ws layout (float offsets)
#define OFF_SPART 0                               // [B][RCH][DIM]
#define OFF_WT    (OFF_SPART + BATCH*RCH*DIM)     // [KTOT][DIM]
#define OFF_U     (OFF_WT + KTOT*DIM)             // [B][NCAP][DIM]
#define OFF_VP    (OFF_U + BATCH*NCAP*DIM)        // [B][RCH][NCAP][DIM]
// total = 4,915,200 floats = 19.66 MB

__device__ __forceinline__ unsigned short f2bf(float f) {
  unsigned u = __float_as_uint(f);
  u += 0x7fffu + ((u >> 16) & 1u);    // RNE
  return (unsigned short)(u >> 16);
}
__device__ __forceinline__ float bflo(unsigned v) { return __uint_as_float(v << 16); }
__device__ __forceinline__ float bfhi(unsigned v) { return __uint_as_float(v & 0xffff0000u); }

// ---------------- kernel 1: column-sum partials + W transpose ----------------
__global__ __launch_bounds__(256)
void k_pre(const float* __restrict__ x, const float* __restrict__ w,
           float* __restrict__ ws) {
  int b = blockIdx.y;
  int t = threadIdx.x;
  if (b == BATCH) {                       // 8 blocks transpose W -> WT[k][d]
    float* wt = ws + OFF_WT;
    int k0 = blockIdx.x * 64;
    for (int it = 0; it < 32; ++it) {
      int f = it * 256 + t;
      int k = k0 + (f >> 7);
      int d = f & 127;
      wt[k * DIM + d] = w[d * KTOT + k];
    }
    return;
  }
  int g = t & 31, r0 = t >> 5;
  const float4* xb = (const float4*)(x + (size_t)b * SEQ * DIM);
  int base = blockIdx.x * RROWS;
  float4 acc = make_float4(0.f, 0.f, 0.f, 0.f);
  for (int r = r0; r < RROWS; r += 8) {
    float4 v = xb[(size_t)(base + r) * 32 + g];
    acc.x += v.x; acc.y += v.y; acc.z += v.z; acc.w += v.w;
  }
  __shared__ float4 red[8][32];
  red[r0][g] = acc;
  __syncthreads();
  if (t < 32) {
    float4 a = red[0][t];
    #pragma unroll
    for (int rr = 1; rr < 8; ++rr) {
      float4 q = red[rr][t];
      a.x += q.x; a.y += q.y; a.z += q.z; a.w += q.w;
    }
    float* sp = ws + OFF_SPART + ((size_t)b * RCH + blockIdx.x) * DIM;
    ((float4*)sp)[t] = a;
  }
}

// ---------------- kernel 2: squash + u (or final output) ----------------
// MODE 0: in = colsum partials, scale 1/32, write u
// MODE 1: in = vp partials, write u
// MODE 2: in = vp partials, write final output
template<int MODE>
__global__ __launch_bounds__(128)
void k_ou(const float* __restrict__ w, float* __restrict__ ws,
          float* __restrict__ outp) {
  int b = blockIdx.y, bx = blockIdx.x, t = threadIdx.x;
  int k = bx * 128 + t;
  __shared__ float vin[8 * DIM];
  __shared__ float osh[128];

  if (MODE == 0) {
    const float* sp = ws + OFF_SPART + (size_t)b * RCH * DIM;
    float s = 0.f;
    for (int c = 0; c < RCH; ++c) s += sp[c * DIM + t];
    vin[t] = s;
  } else {
    const float* vp = ws + OFF_VP + (size_t)b * RCH * NCAP * DIM + (size_t)bx * 8 * DIM;
    for (int j = 0; j < 8; ++j) {
      float s = 0.f;
      for (int c = 0; c < RCH; ++c)
        s += vp[(size_t)c * NCAP * DIM + j * DIM + t];
      vin[j * DIM + t] = s;
    }
  }
  __syncthreads();

  int nl = t >> 4;                        // local capsule 0..7
  const float* vrow = (MODE == 0) ? vin : (vin + nl * DIM);
  float p = 0.f;
  for (int d = 0; d < DIM; ++d) p += vrow[d] * w[d * KTOT + k];
  if (MODE == 0) p *= (1.0f / 32.0f);

  float sq = p * p;
  sq += __shfl_xor(sq, 1, 16);
  sq += __shfl_xor(sq, 2, 16);
  sq += __shfl_xor(sq, 4, 16);
  sq += __shfl_xor(sq, 8, 16);
  sq += EPS_;
  float scale = sqrtf(sq) / (0.5f + sq);
  float o = scale * p;

  if (MODE == 2) { outp[(size_t)b * KTOT + k] = o; return; }

  osh[t] = o;
  __syncthreads();

  // u[n][d] = sum_dc WT[n*16+dc][d] * o[n][dc], n = bx*8 + j, d = t
  const float* wt = ws + OFF_WT;
  float* uo = ws + OFF_U + (size_t)b * NCAP * DIM;
  for (int j = 0; j < 8; ++j) {
    int n = bx * 8 + j;
    float a = 0.f;
    #pragma unroll
    for (int dc = 0; dc < DCAPS; ++dc)
      a += wt[(size_t)(n * DCAPS + dc) * DIM + t] * osh[j * DCAPS + dc];
    uo[(size_t)n * DIM + t] = a;
  }
}

// ---------------- kernel 3: routing pass (dots -> softmax -> v partials) ----------------
__global__ __launch_bounds__(256)
void k_route(const float* __restrict__ x, const float* __restrict__ u,
             float* __restrict__ vp) {
  int b = blockIdx.y, ch = blockIdx.x, t = threadIdx.x;
  __shared__ __align__(16) unsigned short xl[RROWS * DIM];      // bf16, swizzled (32 KB)
  __shared__ __align__(16) unsigned short ct[NCAP][RROWS + 8];  // softmax coeffs bf16
  __shared__ float exm[2][RROWS];
  __shared__ float exs[2][RROWS];

  const float* xb = x + ((size_t)b * SEQ + (size_t)ch * RROWS) * DIM;

  // stage X chunk -> bf16 LDS with XOR swizzle (byte ^= (row&7)<<4)
  for (int it = 0; it < 16; ++it) {
    int f = it * 256 + t;
    int row = f >> 5, g4 = f & 31;
    float4 v = ((const float4*)xb)[(size_t)row * 32 + g4];
    unsigned p0 = (unsigned)f2bf(v.x) | ((unsigned)f2bf(v.y) << 16);
    unsigned p1 = (unsigned)f2bf(v.z) | ((unsigned)f2bf(v.w) << 16);
    int byteoff = row * 256 + ((g4 * 8) ^ ((row & 7) << 4));
    *(uint2*)((char*)xl + byteoff) = make_uint2(p0, p1);
  }
  __syncthreads();

  // ---- phase A: b[n] = X[r,:] . u[n,:]  (u via wave-uniform scalar loads) ----
  int r  = t & 127;
  int nq = __builtin_amdgcn_readfirstlane(t >> 7);   // wave-uniform half select
  const float* ub = u + ((size_t)b * NCAP + (size_t)nq * 16) * DIM;

  float acc[16];
  #pragma unroll
  for (int j = 0; j < 16; ++j) acc[j] = 0.f;

  for (int g = 0; g < 16; ++g) {
    int byteoff = r * 256 + ((g * 16) ^ ((r & 7) << 4));
    uint4 q = *(const uint4*)((const char*)xl + byteoff);
    float xv[8];
    xv[0] = bflo(q.x); xv[1] = bfhi(q.x);
    xv[2] = bflo(q.y); xv[3] = bfhi(q.y);
    xv[4] = bflo(q.z); xv[5] = bfhi(q.z);
    xv[6] = bflo(q.w); xv[7] = bfhi(q.w);
    #pragma unroll
    for (int n = 0; n < 16; ++n) {
      const float* un = ub + (size_t)n * DIM + g * 8;
      float a = acc[n];
      #pragma unroll
      for (int e = 0; e < 8; ++e) a += un[e] * xv[e];
      acc[n] = a;
    }
  }

  // ---- softmax over 32 capsules (two 16-halves exchange via LDS) ----
  float m = acc[0];
  #pragma unroll
  for (int j = 1; j < 16; ++j) m = fmaxf(m, acc[j]);
  exm[nq][r] = m;
  __syncthreads();
  float M = fmaxf(m, exm[nq ^ 1][r]);
  float e[16], ssum = 0.f;
  #pragma unroll
  for (int j = 0; j < 16; ++j) { e[j] = __expf(acc[j] - M); ssum += e[j]; }
  exs[nq][r] = ssum;
  __syncthreads();
  float S = ssum + exs[nq ^ 1][r];
  float inv = 1.0f / S;
  #pragma unroll
  for (int j = 0; j < 16; ++j)
    ct[nq * 16 + j][r] = f2bf(e[j] * inv);
  __syncthreads();

  // ---- phase C: v[n][d] = sum_r c[n][r] * X[r][d], register accumulation ----
  int np = t >> 4;          // 0..15 -> capsules n0, n0+1
  int dg = t & 15;          // d slice: dg*8 .. dg*8+7
  int n0 = np * 2;
  float va0[8], va1[8];
  #pragma unroll
  for (int q2 = 0; q2 < 8; ++q2) { va0[q2] = 0.f; va1[q2] = 0.f; }

  for (int rg = 0; rg < 16; ++rg) {
    uint4 c0 = *(const uint4*)&ct[n0][rg * 8];
    uint4 c1 = *(const uint4*)&ct[n0 + 1][rg * 8];
    float c0f[8], c1f[8];
    c0f[0]=bflo(c0.x); c0f[1]=bfhi(c0.x); c0f[2]=bflo(c0.y); c0f[3]=bfhi(c0.y);
    c0f[4]=bflo(c0.z); c0f[5]=bfhi(c0.z); c0f[6]=bflo(c0.w); c0f[7]=bfhi(c0.w);
    c1f[0]=bflo(c1.x); c1f[1]=bfhi(c1.x); c1f[2]=bflo(c1.y); c1f[3]=bfhi(c1.y);
    c1f[4]=bflo(c1.z); c1f[5]=bfhi(c1.z); c1f[6]=bflo(c1.w); c1f[7]=bfhi(c1.w);
    #pragma unroll
    for (int rr = 0; rr < 8; ++rr) {
      int row = rg * 8 + rr;
      int byteoff = row * 256 + ((dg * 16) ^ ((row & 7) << 4));
      uint4 q = *(const uint4*)((const char*)xl + byteoff);
      float xv[8];
      xv[0] = bflo(q.x); xv[1] = bfhi(q.x);
      xv[2] = bflo(q.y); xv[3] = bfhi(q.y);
      xv[4] = bflo(q.z); xv[5] = bfhi(q.z);
      xv[6] = bflo(q.w); xv[7] = bfhi(q.w);
      float cc0 = c0f[rr], cc1 = c1f[rr];
      #pragma unroll
      for (int q2 = 0; q2 < 8; ++q2) {
        va0[q2] += cc0 * xv[q2];
        va1[q2] += cc1 * xv[q2];
      }
    }
  }

  float* vo = vp + (((size_t)b * RCH + ch) * NCAP) * DIM;
  float4 w0 = make_float4(va0[0], va0[1], va0[2], va0[3]);
  float4 w1 = make_float4(va0[4], va0[5], va0[6], va0[7]);
  float4 w2 = make_float4(va1[0], va1[1], va1[2], va1[3]);
  float4 w3 = make_float4(va1[4], va1[5], va1[6], va1[7]);
  float4* o0 = (float4*)(vo + (size_t)n0 * DIM + dg * 8);
  float4* o1 = (float4*)(vo + (size_t)(n0 + 1) * DIM + dg * 8);
  o0[0] = w0; o0[1] = w1;
  o1[0] = w2; o1[1] = w3;
}

extern "C" void kernel_launch(void* const* d_in, const int* in_sizes, int n_in,
                              void* d_out, int out_size, void* d_ws, size_t ws_size,
                              hipStream_t stream) {
  (void)in_sizes; (void)n_in; (void)out_size; (void)ws_size;
  const float* x = (const float*)d_in[0];
  const float* w = (const float*)d_in[1];   // kernel[0] : [128][512]
  float* out = (float*)d_out;
  float* ws  = (float*)d_ws;
  float* wsu  = ws + OFF_U;
  float* wsvp = ws + OFF_VP;

  k_pre<<<dim3(8, BATCH + 1), 256, 0, stream>>>(x, w, ws);
  k_ou<0><<<dim3(4, BATCH), 128, 0, stream>>>(w, ws, out);
  k_route<<<dim3(RCH, BATCH), 256, 0, stream>>>(x, wsu, wsvp);
  k_ou<1><<<dim3(4, BATCH), 128, 0, stream>>>(w, ws, out);
  k_route<<<dim3(RCH, BATCH), 256, 0, stream>>>(x, wsu, wsvp);
  k_ou<2><<<dim3(4, BATCH), 128, 0, stream>>>(w, ws, out);
}

// Round 2
// 109.883 us; speedup vs baseline: 1.9398x; 1.9398x over previous
//
#include <hip/hip_runtime.h>

#define BATCH 128
#define SEQ   1024
#define DIM   128
#define NCAP  32
#define DCAPS 16
#define KTOT  512
#define EPS_  1e-7f
#define RCH   8
#define RROWS 128

// ws layout (float offsets)
#define OFF_SPART 0                               // [B][RCH][DIM]
#define OFF_WT    (OFF_SPART + BATCH*RCH*DIM)     // [KTOT][DIM]
#define OFF_U     (OFF_WT + KTOT*DIM)             // [B][NCAP][DIM]
#define OFF_VP    (OFF_U + BATCH*NCAP*DIM)        // [B][RCH][NCAP][DIM]

typedef __attribute__((ext_vector_type(8))) short short8v;   // 8 bf16 (4 VGPRs)
typedef __attribute__((ext_vector_type(4))) float f32x4;

__device__ __forceinline__ unsigned short f2bf(float f) {
  unsigned u = __float_as_uint(f);
  u += 0x7fffu + ((u >> 16) & 1u);    // RNE
  return (unsigned short)(u >> 16);
}

__device__ __forceinline__ short8v pk8(float4 a, float4 b) {
  const float* fa = (const float*)&a;
  const float* fb = (const float*)&b;
  short8v r;
  r[0] = (short)f2bf(fa[0]); r[1] = (short)f2bf(fa[1]);
  r[2] = (short)f2bf(fa[2]); r[3] = (short)f2bf(fa[3]);
  r[4] = (short)f2bf(fb[0]); r[5] = (short)f2bf(fb[1]);
  r[6] = (short)f2bf(fb[2]); r[7] = (short)f2bf(fb[3]);
  return r;
}

// ---------------- kernel 1: column-sum partials + W transpose ----------------
__global__ __launch_bounds__(256)
void k_pre(const float* __restrict__ x, const float* __restrict__ w,
           float* __restrict__ ws) {
  int b = blockIdx.y;
  int t = threadIdx.x;
  if (b == BATCH) {                       // 8 blocks transpose W -> WT[k][d]
    float* wt = ws + OFF_WT;
    int k0 = blockIdx.x * 64;
    for (int it = 0; it < 32; ++it) {
      int f = it * 256 + t;
      int k = k0 + (f >> 7);
      int d = f & 127;
      wt[k * DIM + d] = w[d * KTOT + k];
    }
    return;
  }
  int g = t & 31, r0 = t >> 5;
  const float4* xb = (const float4*)(x + (size_t)b * SEQ * DIM);
  int base = blockIdx.x * RROWS;
  float4 acc = make_float4(0.f, 0.f, 0.f, 0.f);
  for (int r = r0; r < RROWS; r += 8) {
    float4 v = xb[(size_t)(base + r) * 32 + g];
    acc.x += v.x; acc.y += v.y; acc.z += v.z; acc.w += v.w;
  }
  __shared__ float4 red[8][32];
  red[r0][g] = acc;
  __syncthreads();
  if (t < 32) {
    float4 a = red[0][t];
    #pragma unroll
    for (int rr = 1; rr < 8; ++rr) {
      float4 q = red[rr][t];
      a.x += q.x; a.y += q.y; a.z += q.z; a.w += q.w;
    }
    float* sp = ws + OFF_SPART + ((size_t)b * RCH + blockIdx.x) * DIM;
    ((float4*)sp)[t] = a;
  }
}

// ---------------- kernel 2: squash + u (or final output) ----------------
template<int MODE>
__global__ __launch_bounds__(128)
void k_ou(const float* __restrict__ w, float* __restrict__ ws,
          float* __restrict__ outp) {
  int b = blockIdx.y, bx = blockIdx.x, t = threadIdx.x;
  int k = bx * 128 + t;
  __shared__ float vin[8 * DIM];
  __shared__ float osh[128];

  if (MODE == 0) {
    const float* sp = ws + OFF_SPART + (size_t)b * RCH * DIM;
    float s = 0.f;
    for (int c = 0; c < RCH; ++c) s += sp[c * DIM + t];
    vin[t] = s;
  } else {
    const float* vp = ws + OFF_VP + (size_t)b * RCH * NCAP * DIM + (size_t)bx * 8 * DIM;
    for (int j = 0; j < 8; ++j) {
      float s = 0.f;
      for (int c = 0; c < RCH; ++c)
        s += vp[(size_t)c * NCAP * DIM + j * DIM + t];
      vin[j * DIM + t] = s;
    }
  }
  __syncthreads();

  int nl = t >> 4;                        // local capsule 0..7
  const float* vrow = (MODE == 0) ? vin : (vin + nl * DIM);
  float p = 0.f;
  for (int d = 0; d < DIM; ++d) p += vrow[d] * w[d * KTOT + k];
  if (MODE == 0) p *= (1.0f / 32.0f);

  float sq = p * p;
  sq += __shfl_xor(sq, 1, 16);
  sq += __shfl_xor(sq, 2, 16);
  sq += __shfl_xor(sq, 4, 16);
  sq += __shfl_xor(sq, 8, 16);
  sq += EPS_;
  float scale = sqrtf(sq) / (0.5f + sq);
  float o = scale * p;

  if (MODE == 2) { outp[(size_t)b * KTOT + k] = o; return; }

  osh[t] = o;
  __syncthreads();

  const float* wt = ws + OFF_WT;
  float* uo = ws + OFF_U + (size_t)b * NCAP * DIM;
  for (int j = 0; j < 8; ++j) {
    int n = bx * 8 + j;
    float a = 0.f;
    #pragma unroll
    for (int dc = 0; dc < DCAPS; ++dc)
      a += wt[(size_t)(n * DCAPS + dc) * DIM + t] * osh[j * DCAPS + dc];
    uo[(size_t)n * DIM + t] = a;
  }
}

// ---------------- kernel 3: MFMA routing pass ----------------
// Phase A: S[r][n] = X.u^T via mfma (A = X rows from global, B = u rows from global)
// softmax in-register -> ct[n][r] bf16 LDS
// Phase C: V^T[d][n] = X^T.c via mfma (A = xt rows (LDS transposed X), B = ct rows)
__global__ __launch_bounds__(256)
void k_route(const float* __restrict__ x, const float* __restrict__ u,
             float* __restrict__ vp) {
  __shared__ __align__(16) unsigned short xt_s[RROWS * DIM];  // X^T bf16, 8B-swizzled (32 KB)
  __shared__ __align__(16) unsigned short ct_s[NCAP * RROWS]; // c[n][r] bf16, 16B-swizzled (8 KB)

  int b = blockIdx.y, ch = blockIdx.x, t = threadIdx.x;
  int wv = t >> 6;            // wave 0..3
  int l  = t & 63;
  int q  = l >> 4;            // lane quarter
  int lr = l & 15;

  const float* xb = x + ((size_t)b * SEQ + (size_t)ch * RROWS) * DIM;
  const float4* X4 = (const float4*)xb;

  // ---- stage X^T into LDS (bf16, swizzle byte ^= (d&31)<<3) ----
  #pragma unroll
  for (int i = 0; i < 4; ++i) {
    int fb = i * 256 + t;
    int seg = fb >> 6;
    int db = (seg & 3) * 8 + (fb & 7);          // d-block 0..31
    int rb = (seg >> 2) * 8 + ((fb >> 3) & 7);  // r-block 0..31
    float4 r0 = X4[(size_t)(4 * rb + 0) * 32 + db];
    float4 r1 = X4[(size_t)(4 * rb + 1) * 32 + db];
    float4 r2 = X4[(size_t)(4 * rb + 2) * 32 + db];
    float4 r3 = X4[(size_t)(4 * rb + 3) * 32 + db];
    const float* p0 = (const float*)&r0; const float* p1 = (const float*)&r1;
    const float* p2 = (const float*)&r2; const float* p3 = (const float*)&r3;
    #pragma unroll
    for (int w2 = 0; w2 < 4; ++w2) {
      int d = 4 * db + w2;
      unsigned lo = (unsigned)f2bf(p0[w2]) | ((unsigned)f2bf(p1[w2]) << 16);
      unsigned hi = (unsigned)f2bf(p2[w2]) | ((unsigned)f2bf(p3[w2]) << 16);
      int off = d * 256 + ((8 * rb) ^ ((d & 31) << 3));
      *(uint2*)((char*)xt_s + off) = make_uint2(lo, hi);
    }
  }

  // ---- phase A frag loads (global, L2-warm after staging reads) ----
  short8v afr[2][4];          // A = X[r][k], r = wv*32+mt*16+lr, k = kk*32+q*8..
  #pragma unroll
  for (int mt = 0; mt < 2; ++mt) {
    const float* arow = xb + (size_t)(wv * 32 + mt * 16 + lr) * DIM;
    #pragma unroll
    for (int kk = 0; kk < 4; ++kk) {
      const float4* p = (const float4*)(arow + kk * 32 + q * 8);
      afr[mt][kk] = pk8(p[0], p[1]);
    }
  }
  const float* ub = u + (size_t)b * NCAP * DIM;
  short8v bfr[2][4];          // B = u[n][k]
  #pragma unroll
  for (int nt = 0; nt < 2; ++nt) {
    const float* urow = ub + (size_t)(nt * 16 + lr) * DIM;
    #pragma unroll
    for (int kk = 0; kk < 4; ++kk) {
      const float4* p = (const float4*)(urow + kk * 32 + q * 8);
      bfr[nt][kk] = pk8(p[0], p[1]);
    }
  }

  f32x4 acc[2][2];
  #pragma unroll
  for (int mt = 0; mt < 2; ++mt)
    #pragma unroll
    for (int nt = 0; nt < 2; ++nt)
      acc[mt][nt] = (f32x4){0.f, 0.f, 0.f, 0.f};

  #pragma unroll
  for (int kk = 0; kk < 4; ++kk)
    #pragma unroll
    for (int mt = 0; mt < 2; ++mt)
      #pragma unroll
      for (int nt = 0; nt < 2; ++nt)
        acc[mt][nt] = __builtin_amdgcn_mfma_f32_16x16x32_bf16(
            afr[mt][kk], bfr[nt][kk], acc[mt][nt], 0, 0, 0);

  // ---- softmax over n (32) per row; write c -> ct[n][r] bf16 ----
  // C-frag: lane holds S[row = mt*16 + q*4 + j][n = nt*16 + lr]
  #pragma unroll
  for (int mt = 0; mt < 2; ++mt) {
    #pragma unroll
    for (int j = 0; j < 4; ++j) {
      float v0 = acc[mt][0][j], v1 = acc[mt][1][j];
      float m2 = fmaxf(v0, v1);
      m2 = fmaxf(m2, __shfl_xor(m2, 1, 16));
      m2 = fmaxf(m2, __shfl_xor(m2, 2, 16));
      m2 = fmaxf(m2, __shfl_xor(m2, 4, 16));
      m2 = fmaxf(m2, __shfl_xor(m2, 8, 16));
      float e0 = __expf(v0 - m2), e1 = __expf(v1 - m2);
      float s2 = e0 + e1;
      s2 += __shfl_xor(s2, 1, 16);
      s2 += __shfl_xor(s2, 2, 16);
      s2 += __shfl_xor(s2, 4, 16);
      s2 += __shfl_xor(s2, 8, 16);
      float inv = 1.0f / s2;
      int R = wv * 32 + mt * 16 + q * 4 + j;
      int n0 = lr, n1 = 16 + lr;
      int sw = (lr & 7) << 4;
      *(unsigned short*)((char*)ct_s + n0 * 256 + ((2 * R) ^ sw)) = f2bf(e0 * inv);
      *(unsigned short*)((char*)ct_s + n1 * 256 + ((2 * R) ^ sw)) = f2bf(e1 * inv);
    }
  }

  __syncthreads();   // xt_s + ct_s ready

  // ---- phase C: V^T[d][n] = sum_r X^T[d][r] c^T[r][n] ----
  f32x4 vac[2][2];
  #pragma unroll
  for (int mt = 0; mt < 2; ++mt)
    #pragma unroll
    for (int nt = 0; nt < 2; ++nt)
      vac[mt][nt] = (f32x4){0.f, 0.f, 0.f, 0.f};

  #pragma unroll
  for (int kk = 0; kk < 4; ++kk) {
    union { short8v v; uint2 u2[2]; } ax[2];
    #pragma unroll
    for (int mt = 0; mt < 2; ++mt) {
      int d = wv * 32 + mt * 16 + lr;
      int sw = (d & 31) << 3;
      int base = d * 256;
      int c0 = kk * 64 + q * 16;
      ax[mt].u2[0] = *(const uint2*)((const char*)xt_s + base + (c0 ^ sw));
      ax[mt].u2[1] = *(const uint2*)((const char*)xt_s + base + ((c0 + 8) ^ sw));
    }
    short8v bx[2];
    #pragma unroll
    for (int nt = 0; nt < 2; ++nt) {
      int n = nt * 16 + lr;
      int byteoff = n * 256 + ((kk * 64 + q * 16) ^ ((n & 7) << 4));
      bx[nt] = *(const short8v*)((const char*)ct_s + byteoff);
    }
    #pragma unroll
    for (int mt = 0; mt < 2; ++mt)
      #pragma unroll
      for (int nt = 0; nt < 2; ++nt)
        vac[mt][nt] = __builtin_amdgcn_mfma_f32_16x16x32_bf16(
            ax[mt].v, bx[nt], vac[mt][nt], 0, 0, 0);
  }

  // C-frag: lane holds V^T[d = mt*16 + q*4 + j][n = nt*16 + lr]
  float* vo = vp + ((size_t)(b * RCH + ch) * NCAP) * DIM;
  #pragma unroll
  for (int mt = 0; mt < 2; ++mt)
    #pragma unroll
    for (int nt = 0; nt < 2; ++nt) {
      int n = nt * 16 + lr;
      int d0 = wv * 32 + mt * 16 + q * 4;
      *(f32x4*)(vo + (size_t)n * DIM + d0) = vac[mt][nt];
    }
}

extern "C" void kernel_launch(void* const* d_in, const int* in_sizes, int n_in,
                              void* d_out, int out_size, void* d_ws, size_t ws_size,
                              hipStream_t stream) {
  (void)in_sizes; (void)n_in; (void)out_size; (void)ws_size;
  const float* x = (const float*)d_in[0];
  const float* w = (const float*)d_in[1];   // kernel[0] : [128][512]
  float* out = (float*)d_out;
  float* ws  = (float*)d_ws;
  float* wsu  = ws + OFF_U;
  float* wsvp = ws + OFF_VP;

  k_pre<<<dim3(8, BATCH + 1), 256, 0, stream>>>(x, w, ws);
  k_ou<0><<<dim3(4, BATCH), 128, 0, stream>>>(w, ws, out);
  k_route<<<dim3(RCH, BATCH), 256, 0, stream>>>(x, wsu, wsvp);
  k_ou<1><<<dim3(4, BATCH), 128, 0, stream>>>(w, ws, out);
  k_route<<<dim3(RCH, BATCH), 256, 0, stream>>>(x, wsu, wsvp);
  k_ou<2><<<dim3(4, BATCH), 128, 0, stream>>>(w, ws, out);
}

// Round 4
// 91.949 us; speedup vs baseline: 2.3182x; 1.1950x over previous
//
#include <hip/hip_runtime.h>

#define BATCH 128
#define SEQ   1024
#define DIM   128
#define NCAP  32
#define DCAPS 16
#define KTOT  512
#define EPS_  1e-7f
#define RCH   8
#define RROWS 128

// ws layout (float offsets). ws = 256MiB per harness fill counters; we use ~86MB.
#define OFF_SPART 0                                  // [B][RCH][DIM] f32
#define OFF_WT    (OFF_SPART + BATCH*RCH*DIM)        // [KTOT][DIM] f32
#define OFF_UBF   (OFF_WT + KTOT*DIM)                // [B][NCAP][DIM] bf16 (as ushort)
#define OFF_VP    (OFF_UBF + BATCH*NCAP*DIM/2)       // [B][RCH][NCAP][DIM] f32
#define OFF_XROW  (OFF_VP + BATCH*RCH*NCAP*DIM)      // [B][SEQ][DIM] bf16
#define OFF_XT    (OFF_XROW + BATCH*SEQ*DIM/2)       // [B][DIM][SEQ] bf16
// end = OFF_XT + BATCH*SEQ*DIM/2 = 21,430,272 floats = 85.7 MB

typedef __attribute__((ext_vector_type(8))) short short8v;   // 8 bf16 (4 VGPRs)
typedef __attribute__((ext_vector_type(4))) float f32x4;
typedef unsigned short ushort_t;

__device__ __forceinline__ unsigned f2bf(float f) {
  unsigned u = __float_as_uint(f);
  u += 0x7fffu + ((u >> 16) & 1u);    // RNE
  return u >> 16;
}
__device__ __forceinline__ uint4 pack8(float4 a, float4 b) {
  uint4 r;
  r.x = f2bf(a.x) | (f2bf(a.y) << 16);
  r.y = f2bf(a.z) | (f2bf(a.w) << 16);
  r.z = f2bf(b.x) | (f2bf(b.y) << 16);
  r.w = f2bf(b.z) | (f2bf(b.w) << 16);
  return r;
}

// ---------- kernel 1: colsum partials + WT transpose + bf16 X images ----------
__global__ __launch_bounds__(256)
void k_pre(const float* __restrict__ x, const float* __restrict__ w,
           float* __restrict__ ws) {
  int t = threadIdx.x;
  if (blockIdx.y == BATCH) {              // 8 blocks transpose W -> WT[k][d]
    float* wt = ws + OFF_WT;
    int k0 = blockIdx.x * 64;
    for (int it = 0; it < 32; ++it) {
      int f = it * 256 + t;
      int k = k0 + (f >> 7);
      int d = f & 127;
      wt[k * DIM + d] = w[d * KTOT + k];
    }
    return;
  }
  int b = blockIdx.y, ch = blockIdx.x;
  __shared__ __align__(16) ushort_t xl[RROWS * DIM];    // bf16 chunk, row-major (32 KB)
  __shared__ float4 red0[16][16];
  __shared__ float4 red1[16][16];

  const float4* X4 = (const float4*)(x + ((size_t)b * SEQ + (size_t)ch * RROWS) * DIM);
  ushort_t* xrow = (ushort_t*)(ws + OFF_XROW) + ((size_t)b * SEQ + (size_t)ch * RROWS) * DIM;
  ushort_t* xt   = (ushort_t*)(ws + OFF_XT)   + (size_t)b * DIM * SEQ;

  int seg = t & 15, grp = t >> 4;
  float4 a0 = make_float4(0.f,0.f,0.f,0.f), a1 = make_float4(0.f,0.f,0.f,0.f);
  // 128 rows / 16 grp-groups = 8 iterations (it<8! r must stay < RROWS)
  for (int it = 0; it < 8; ++it) {
    int r = it * 16 + grp;
    float4 v0 = X4[(size_t)r * 32 + seg * 2];
    float4 v1 = X4[(size_t)r * 32 + seg * 2 + 1];
    a0.x += v0.x; a0.y += v0.y; a0.z += v0.z; a0.w += v0.w;
    a1.x += v1.x; a1.y += v1.y; a1.z += v1.z; a1.w += v1.w;
    uint4 pk = pack8(v0, v1);
    *(uint4*)(xrow + (size_t)r * DIM + seg * 8) = pk;
    *(uint4*)(xl + r * DIM + seg * 8) = pk;
  }
  red0[grp][seg] = a0;
  red1[grp][seg] = a1;
  __syncthreads();

  if (t < 128) {                          // colsum partial for this chunk
    int sg = t >> 3, e = t & 7;
    float s = 0.f;
    for (int g = 0; g < 16; ++g) {
      const float* p0 = (const float*)&red0[g][sg];
      const float* p1 = (const float*)&red1[g][sg];
      s += (e < 4) ? p0[e] : p1[e - 4];
    }
    ws[OFF_SPART + ((size_t)b * RCH + ch) * DIM + t] = s;
  }

  // transposed image: xt[b][d][ch*128 + r]
  for (int j = 0; j < 8; ++j) {
    int f = j * 256 + t;
    int d = f & 127, r8 = (f >> 7) * 8;
    union { ushort_t s[8]; uint4 v; } tmp;
    #pragma unroll
    for (int i = 0; i < 8; ++i) tmp.s[i] = xl[(r8 + i) * DIM + d];
    *(uint4*)(xt + (size_t)d * SEQ + ch * RROWS + r8) = tmp.v;
  }
}

// ---------- kernel 2: squash + u(bf16) (or final output) ----------
template<int MODE>
__global__ __launch_bounds__(128)
void k_ou(float* __restrict__ ws, float* __restrict__ outp) {
  int b = blockIdx.y, bx = blockIdx.x, t = threadIdx.x;
  int k = bx * 128 + t;
  __shared__ float vin[8 * DIM];
  __shared__ float osh[128];

  if (MODE == 0) {
    const float* sp = ws + OFF_SPART + (size_t)b * RCH * DIM;
    float s = 0.f;
    for (int c = 0; c < RCH; ++c) s += sp[c * DIM + t];
    vin[t] = s * (1.0f / 32.0f);
  } else {
    const float* vp = ws + OFF_VP + (size_t)b * RCH * NCAP * DIM + (size_t)bx * 8 * DIM;
    for (int j = 0; j < 8; ++j) {
      float s = 0.f;
      for (int c = 0; c < RCH; ++c)
        s += vp[(size_t)c * NCAP * DIM + j * DIM + t];
      vin[j * DIM + t] = s;
    }
  }
  __syncthreads();

  int nl = t >> 4;
  const float4* vr = (const float4*)((MODE == 0) ? vin : (vin + nl * DIM));
  const float4* wtr = (const float4*)(ws + OFF_WT + (size_t)k * DIM);
  float p = 0.f;
  #pragma unroll 8
  for (int i = 0; i < 32; ++i) {
    float4 wv = wtr[i], vv = vr[i];
    p += wv.x * vv.x + wv.y * vv.y + wv.z * vv.z + wv.w * vv.w;
  }

  float sq = p * p;
  sq += __shfl_xor(sq, 1, 16);
  sq += __shfl_xor(sq, 2, 16);
  sq += __shfl_xor(sq, 4, 16);
  sq += __shfl_xor(sq, 8, 16);
  sq += EPS_;
  float scale = sqrtf(sq) / (0.5f + sq);
  float o = scale * p;

  if (MODE == 2) { outp[(size_t)b * KTOT + k] = o; return; }

  osh[t] = o;
  __syncthreads();

  const float* wt = ws + OFF_WT;
  ushort_t* ubf = (ushort_t*)(ws + OFF_UBF) + (size_t)b * NCAP * DIM;
  for (int j = 0; j < 8; ++j) {
    int n = bx * 8 + j;
    float a = 0.f;
    #pragma unroll
    for (int dc = 0; dc < DCAPS; ++dc)
      a += wt[(size_t)(n * DCAPS + dc) * DIM + t] * osh[j * DCAPS + dc];
    ubf[(size_t)n * DIM + t] = (ushort_t)f2bf(a);
  }
}

// ---------- kernel 3: MFMA routing pass, no staging ----------
// Phase A: S^T[n][r] = u.X^T  (A = u rows bf16, B = X rows bf16, both global)
// softmax over n: in-lane (8 vals) + 2 shfl; c -> ct_s bf16 LDS
// Phase C: V^T[d][n] = X^T.c  (A = xt image rows, B = ct rows)
__global__ __launch_bounds__(256)
void k_route(const float* __restrict__ ws_c, float* __restrict__ vp) {
  __shared__ __align__(16) ushort_t ct_s[NCAP * RROWS];   // c[n][r] bf16, swizzled (8 KB)

  int b = blockIdx.y, ch = blockIdx.x, t = threadIdx.x;
  int wv = t >> 6;
  int l  = t & 63;
  int q  = l >> 4;
  int lr = l & 15;

  const ushort_t* ubf  = (const ushort_t*)(ws_c + OFF_UBF) + (size_t)b * NCAP * DIM;
  const ushort_t* xrow = (const ushort_t*)(ws_c + OFF_XROW) + ((size_t)b * SEQ + (size_t)ch * RROWS) * DIM;
  const ushort_t* xt   = (const ushort_t*)(ws_c + OFF_XT)   + (size_t)b * DIM * SEQ + (size_t)ch * RROWS;

  // ---- phase A frags ----
  short8v ufr[2][4], xfr[2][4];
  #pragma unroll
  for (int nt = 0; nt < 2; ++nt)
    #pragma unroll
    for (int kk = 0; kk < 4; ++kk)
      ufr[nt][kk] = *(const short8v*)(ubf + (size_t)(nt * 16 + lr) * DIM + kk * 32 + q * 8);
  #pragma unroll
  for (int rt = 0; rt < 2; ++rt)
    #pragma unroll
    for (int kk = 0; kk < 4; ++kk)
      xfr[rt][kk] = *(const short8v*)(xrow + (size_t)(wv * 32 + rt * 16 + lr) * DIM + kk * 32 + q * 8);

  f32x4 acc[2][2];
  #pragma unroll
  for (int rt = 0; rt < 2; ++rt)
    #pragma unroll
    for (int nt = 0; nt < 2; ++nt)
      acc[rt][nt] = (f32x4){0.f, 0.f, 0.f, 0.f};

  #pragma unroll
  for (int kk = 0; kk < 4; ++kk)
    #pragma unroll
    for (int rt = 0; rt < 2; ++rt)
      #pragma unroll
      for (int nt = 0; nt < 2; ++nt)
        acc[rt][nt] = __builtin_amdgcn_mfma_f32_16x16x32_bf16(
            ufr[nt][kk], xfr[rt][kk], acc[rt][nt], 0, 0, 0);

  // ---- issue phase C A-frag loads early (hide under softmax) ----
  short8v axfr[2][4];
  #pragma unroll
  for (int dt = 0; dt < 2; ++dt)
    #pragma unroll
    for (int kk = 0; kk < 4; ++kk)
      axfr[dt][kk] = *(const short8v*)(xt + (size_t)(wv * 32 + dt * 16 + lr) * SEQ + kk * 32 + q * 8);

  // ---- softmax over n (in-lane 8 + shfl over q-lanes) ----
  // lane holds S^T[n = nt*16 + q*4 + j][r = wv*32 + rt*16 + lr]
  #pragma unroll
  for (int rt = 0; rt < 2; ++rt) {
    float v[8];
    #pragma unroll
    for (int nt = 0; nt < 2; ++nt)
      #pragma unroll
      for (int j = 0; j < 4; ++j) v[nt * 4 + j] = acc[rt][nt][j];
    float m = v[0];
    #pragma unroll
    for (int i = 1; i < 8; ++i) m = fmaxf(m, v[i]);
    m = fmaxf(m, __shfl_xor(m, 16));
    m = fmaxf(m, __shfl_xor(m, 32));
    float e[8], s = 0.f;
    #pragma unroll
    for (int i = 0; i < 8; ++i) { e[i] = __expf(v[i] - m); s += e[i]; }
    s += __shfl_xor(s, 16);
    s += __shfl_xor(s, 32);
    float inv = 1.0f / s;
    int r = wv * 32 + rt * 16 + lr;
    int rs = r >> 3, rb = (r & 7) * 2;
    #pragma unroll
    for (int nt = 0; nt < 2; ++nt)
      #pragma unroll
      for (int j = 0; j < 4; ++j) {
        int n = nt * 16 + q * 4 + j;
        *(ushort_t*)((char*)ct_s + n * 256 + ((rs ^ (n & 15)) << 4) + rb) =
            (ushort_t)f2bf(e[nt * 4 + j] * inv);
      }
  }

  __syncthreads();

  // ---- phase C ----
  short8v bc[2][4];
  #pragma unroll
  for (int nt = 0; nt < 2; ++nt) {
    int n2 = nt * 16 + lr;
    #pragma unroll
    for (int kk = 0; kk < 4; ++kk)
      bc[nt][kk] = *(const short8v*)((char*)ct_s + n2 * 256 + (((4 * kk + q) ^ (n2 & 15)) << 4));
  }

  f32x4 vac[2][2];
  #pragma unroll
  for (int dt = 0; dt < 2; ++dt)
    #pragma unroll
    for (int nt = 0; nt < 2; ++nt)
      vac[dt][nt] = (f32x4){0.f, 0.f, 0.f, 0.f};

  #pragma unroll
  for (int kk = 0; kk < 4; ++kk)
    #pragma unroll
    for (int dt = 0; dt < 2; ++dt)
      #pragma unroll
      for (int nt = 0; nt < 2; ++nt)
        vac[dt][nt] = __builtin_amdgcn_mfma_f32_16x16x32_bf16(
            axfr[dt][kk], bc[nt][kk], vac[dt][nt], 0, 0, 0);

  // lane holds V^T[d = wv*32 + dt*16 + q*4 + j][n = nt*16 + lr]
  float* vo = vp + ((size_t)(b * RCH + ch) * NCAP) * DIM;
  #pragma unroll
  for (int dt = 0; dt < 2; ++dt)
    #pragma unroll
    for (int nt = 0; nt < 2; ++nt) {
      int n = nt * 16 + lr;
      int d0 = wv * 32 + dt * 16 + q * 4;
      *(f32x4*)(vo + (size_t)n * DIM + d0) = vac[dt][nt];
    }
}

extern "C" void kernel_launch(void* const* d_in, const int* in_sizes, int n_in,
                              void* d_out, int out_size, void* d_ws, size_t ws_size,
                              hipStream_t stream) {
  (void)in_sizes; (void)n_in; (void)out_size; (void)ws_size;
  const float* x = (const float*)d_in[0];
  const float* w = (const float*)d_in[1];   // kernel[0] : [128][512]
  float* out = (float*)d_out;
  float* ws  = (float*)d_ws;
  float* wsvp = ws + OFF_VP;

  k_pre<<<dim3(8, BATCH + 1), 256, 0, stream>>>(x, w, ws);
  k_ou<0><<<dim3(4, BATCH), 128, 0, stream>>>(ws, out);
  k_route<<<dim3(RCH, BATCH), 256, 0, stream>>>(ws, wsvp);
  k_ou<1><<<dim3(4, BATCH), 128, 0, stream>>>(ws, out);
  k_route<<<dim3(RCH, BATCH), 256, 0, stream>>>(ws, wsvp);
  k_ou<2><<<dim3(4, BATCH), 128, 0, stream>>>(ws, out);
}

// Round 5
// 84.974 us; speedup vs baseline: 2.5084x; 1.0821x over previous
//
#include <hip/hip_runtime.h>

#define BATCH 128
#define SEQ   1024
#define DIM   128
#define NCAP  32
#define DCAPS 16
#define KTOT  512
#define EPS_  1e-7f
#define RCH   8
#define RROWS 128

// ws layout (float offsets). ws = 256MiB per harness fill counters; we use ~86MB.
#define OFF_SPART 0                                  // [B][RCH][DIM] f32
#define OFF_WT    (OFF_SPART + BATCH*RCH*DIM)        // [KTOT][DIM] f32
#define OFF_UBF   (OFF_WT + KTOT*DIM)                // [B][NCAP][DIM] bf16 (as ushort)
#define OFF_VP    (OFF_UBF + BATCH*NCAP*DIM/2)       // [B][RCH][NCAP][DIM] f32
#define OFF_XROW  (OFF_VP + BATCH*RCH*NCAP*DIM)      // [B][SEQ][DIM] bf16
#define OFF_XT    (OFF_XROW + BATCH*SEQ*DIM/2)       // [B][DIM][SEQ] bf16
// end = OFF_XT + BATCH*SEQ*DIM/2 = 21,430,272 floats = 85.7 MB

typedef __attribute__((ext_vector_type(8))) short short8v;   // 8 bf16 (4 VGPRs)
typedef __attribute__((ext_vector_type(4))) float f32x4;
typedef unsigned short ushort_t;

__device__ __forceinline__ unsigned f2bf(float f) {
  unsigned u = __float_as_uint(f);
  u += 0x7fffu + ((u >> 16) & 1u);    // RNE
  return u >> 16;
}
__device__ __forceinline__ uint4 pack8(float4 a, float4 b) {
  uint4 r;
  r.x = f2bf(a.x) | (f2bf(a.y) << 16);
  r.y = f2bf(a.z) | (f2bf(a.w) << 16);
  r.z = f2bf(b.x) | (f2bf(b.y) << 16);
  r.w = f2bf(b.z) | (f2bf(b.w) << 16);
  return r;
}

// ---------- kernel 1: colsum partials + WT transpose + bf16 X images ----------
__global__ __launch_bounds__(256)
void k_pre(const float* __restrict__ x, const float* __restrict__ w,
           float* __restrict__ ws) {
  int t = threadIdx.x;
  __shared__ __align__(16) char smem[40960];

  if (blockIdx.y == BATCH) {              // 8 blocks: LDS-tiled W transpose
    float* wl = (float*)smem;             // [128][66] padded tile (33.8 KB)
    int k0 = blockIdx.x * 64;
    for (int it = 0; it < 32; ++it) {     // coalesced read: 256B rows of w
      int f = it * 256 + t;
      int kk = f & 63, d = f >> 6;
      wl[d * 66 + kk] = w[d * KTOT + k0 + kk];
    }
    __syncthreads();
    float* wt = ws + OFF_WT;
    for (int it = 0; it < 32; ++it) {     // coalesced write: 512B rows of wt
      int f = it * 256 + t;
      int d = f & 127, kk = f >> 7;
      wt[(size_t)(k0 + kk) * DIM + d] = wl[d * 66 + kk];
    }
    return;
  }
  int b = blockIdx.y, ch = blockIdx.x;
  ushort_t* xl = (ushort_t*)smem;                 // bf16 chunk, 16B-swizzled (32 KB)
  float4* red0 = (float4*)(smem + 32768);         // [16][16] (4 KB)
  float4* red1 = (float4*)(smem + 32768 + 4096);  // [16][16] (4 KB)

  const float4* X4 = (const float4*)(x + ((size_t)b * SEQ + (size_t)ch * RROWS) * DIM);
  ushort_t* xrow = (ushort_t*)(ws + OFF_XROW) + ((size_t)b * SEQ + (size_t)ch * RROWS) * DIM;
  ushort_t* xt   = (ushort_t*)(ws + OFF_XT)   + (size_t)b * DIM * SEQ;

  int seg = t & 15, grp = t >> 4;
  float4 a0 = make_float4(0.f,0.f,0.f,0.f), a1 = make_float4(0.f,0.f,0.f,0.f);
  for (int it = 0; it < 8; ++it) {
    int r = it * 16 + grp;
    float4 v0 = X4[(size_t)r * 32 + seg * 2];
    float4 v1 = X4[(size_t)r * 32 + seg * 2 + 1];
    a0.x += v0.x; a0.y += v0.y; a0.z += v0.z; a0.w += v0.w;
    a1.x += v1.x; a1.y += v1.y; a1.z += v1.z; a1.w += v1.w;
    uint4 pk = pack8(v0, v1);
    *(uint4*)(xrow + (size_t)r * DIM + seg * 8) = pk;     // coalesced 256B
    // swizzled LDS: 16B slot seg ^ ((r>>3)&7) within row r
    *(uint4*)(smem + r * 256 + ((seg << 4) ^ (((r >> 3) & 7) << 4))) = pk;
  }
  red0[grp * 16 + seg] = a0;
  red1[grp * 16 + seg] = a1;
  __syncthreads();

  if (t < 128) {                          // colsum partial for this chunk
    int sg = t >> 3, e = t & 7;
    float s = 0.f;
    for (int g = 0; g < 16; ++g) {
      const float* p0 = (const float*)&red0[g * 16 + sg];
      const float* p1 = (const float*)&red1[g * 16 + sg];
      s += (e < 4) ? p0[e] : p1[e - 4];
    }
    ws[OFF_SPART + ((size_t)b * RCH + ch) * DIM + t] = s;
  }

  // transposed image xt[b][d][ch*128 + r]: 16 consecutive lanes write 256B of row d
  for (int j = 0; j < 8; ++j) {
    int f = j * 256 + t;
    int r8g = f & 15;                     // r-block (r = r8g*8 + i)
    int d   = f >> 4;                     // 0..127
    int dhi = (d >> 3) << 4, dlo = (d & 7) * 2;
    int rsw = (r8g & 7) << 4;             // (r>>3)&7 == r8g&7 for r in this block
    const char* base = smem + ((dhi ^ rsw) + dlo);
    union { ushort_t s[8]; uint4 v; } tmp;
    #pragma unroll
    for (int i = 0; i < 8; ++i)
      tmp.s[i] = *(const ushort_t*)(base + (r8g * 8 + i) * 256);
    *(uint4*)(xt + (size_t)d * SEQ + ch * RROWS + r8g * 8) = tmp.v;
  }
}

// ---------- kernel 2: squash + u(bf16) (or final output) ----------
template<int MODE>
__global__ __launch_bounds__(128)
void k_ou(float* __restrict__ ws, float* __restrict__ outp) {
  int b = blockIdx.y, bx = blockIdx.x, t = threadIdx.x;
  int k = bx * 128 + t;
  __shared__ float vin[8 * DIM];
  __shared__ float osh[128];

  if (MODE == 0) {
    const float* sp = ws + OFF_SPART + (size_t)b * RCH * DIM;
    float s = 0.f;
    for (int c = 0; c < RCH; ++c) s += sp[c * DIM + t];
    vin[t] = s * (1.0f / 32.0f);
  } else {
    const float* vp = ws + OFF_VP + (size_t)b * RCH * NCAP * DIM + (size_t)bx * 8 * DIM;
    for (int j = 0; j < 8; ++j) {
      float s = 0.f;
      for (int c = 0; c < RCH; ++c)
        s += vp[(size_t)c * NCAP * DIM + j * DIM + t];
      vin[j * DIM + t] = s;
    }
  }
  __syncthreads();

  int nl = t >> 4;
  const float4* vr = (const float4*)((MODE == 0) ? vin : (vin + nl * DIM));
  const float4* wtr = (const float4*)(ws + OFF_WT + (size_t)k * DIM);
  float p = 0.f;
  #pragma unroll 8
  for (int i = 0; i < 32; ++i) {
    float4 wv = wtr[i], vv = vr[i];
    p += wv.x * vv.x + wv.y * vv.y + wv.z * vv.z + wv.w * vv.w;
  }

  float sq = p * p;
  sq += __shfl_xor(sq, 1, 16);
  sq += __shfl_xor(sq, 2, 16);
  sq += __shfl_xor(sq, 4, 16);
  sq += __shfl_xor(sq, 8, 16);
  sq += EPS_;
  float scale = sqrtf(sq) / (0.5f + sq);
  float o = scale * p;

  if (MODE == 2) { outp[(size_t)b * KTOT + k] = o; return; }

  osh[t] = o;
  __syncthreads();

  const float* wt = ws + OFF_WT;
  ushort_t* ubf = (ushort_t*)(ws + OFF_UBF) + (size_t)b * NCAP * DIM;
  for (int j = 0; j < 8; ++j) {
    int n = bx * 8 + j;
    float a = 0.f;
    #pragma unroll
    for (int dc = 0; dc < DCAPS; ++dc)
      a += wt[(size_t)(n * DCAPS + dc) * DIM + t] * osh[j * DCAPS + dc];
    ubf[(size_t)n * DIM + t] = (ushort_t)f2bf(a);
  }
}

// ---------- kernel 3: MFMA routing pass, no staging ----------
// Phase A: S^T[n][r] = u.X^T  (A = u rows bf16, B = X rows bf16, both global)
// softmax over n: in-lane (8 vals) + 2 shfl; c -> ct_s bf16 LDS
// Phase C: V^T[d][n] = X^T.c  (A = xt image rows, B = ct rows)
__global__ __launch_bounds__(256)
void k_route(const float* __restrict__ ws_c, float* __restrict__ vp) {
  __shared__ __align__(16) ushort_t ct_s[NCAP * RROWS];   // c[n][r] bf16, swizzled (8 KB)

  int b = blockIdx.y, ch = blockIdx.x, t = threadIdx.x;
  int wv = t >> 6;
  int l  = t & 63;
  int q  = l >> 4;
  int lr = l & 15;

  const ushort_t* ubf  = (const ushort_t*)(ws_c + OFF_UBF) + (size_t)b * NCAP * DIM;
  const ushort_t* xrow = (const ushort_t*)(ws_c + OFF_XROW) + ((size_t)b * SEQ + (size_t)ch * RROWS) * DIM;
  const ushort_t* xt   = (const ushort_t*)(ws_c + OFF_XT)   + (size_t)b * DIM * SEQ + (size_t)ch * RROWS;

  // ---- phase A frags ----
  short8v ufr[2][4], xfr[2][4];
  #pragma unroll
  for (int nt = 0; nt < 2; ++nt)
    #pragma unroll
    for (int kk = 0; kk < 4; ++kk)
      ufr[nt][kk] = *(const short8v*)(ubf + (size_t)(nt * 16 + lr) * DIM + kk * 32 + q * 8);
  #pragma unroll
  for (int rt = 0; rt < 2; ++rt)
    #pragma unroll
    for (int kk = 0; kk < 4; ++kk)
      xfr[rt][kk] = *(const short8v*)(xrow + (size_t)(wv * 32 + rt * 16 + lr) * DIM + kk * 32 + q * 8);

  f32x4 acc[2][2];
  #pragma unroll
  for (int rt = 0; rt < 2; ++rt)
    #pragma unroll
    for (int nt = 0; nt < 2; ++nt)
      acc[rt][nt] = (f32x4){0.f, 0.f, 0.f, 0.f};

  #pragma unroll
  for (int kk = 0; kk < 4; ++kk)
    #pragma unroll
    for (int rt = 0; rt < 2; ++rt)
      #pragma unroll
      for (int nt = 0; nt < 2; ++nt)
        acc[rt][nt] = __builtin_amdgcn_mfma_f32_16x16x32_bf16(
            ufr[nt][kk], xfr[rt][kk], acc[rt][nt], 0, 0, 0);

  // ---- issue phase C A-frag loads early (hide under softmax) ----
  short8v axfr[2][4];
  #pragma unroll
  for (int dt = 0; dt < 2; ++dt)
    #pragma unroll
    for (int kk = 0; kk < 4; ++kk)
      axfr[dt][kk] = *(const short8v*)(xt + (size_t)(wv * 32 + dt * 16 + lr) * SEQ + kk * 32 + q * 8);

  // ---- softmax over n (in-lane 8 + shfl over q-lanes) ----
  // lane holds S^T[n = nt*16 + q*4 + j][r = wv*32 + rt*16 + lr]
  #pragma unroll
  for (int rt = 0; rt < 2; ++rt) {
    float v[8];
    #pragma unroll
    for (int nt = 0; nt < 2; ++nt)
      #pragma unroll
      for (int j = 0; j < 4; ++j) v[nt * 4 + j] = acc[rt][nt][j];
    float m = v[0];
    #pragma unroll
    for (int i = 1; i < 8; ++i) m = fmaxf(m, v[i]);
    m = fmaxf(m, __shfl_xor(m, 16));
    m = fmaxf(m, __shfl_xor(m, 32));
    float e[8], s = 0.f;
    #pragma unroll
    for (int i = 0; i < 8; ++i) { e[i] = __expf(v[i] - m); s += e[i]; }
    s += __shfl_xor(s, 16);
    s += __shfl_xor(s, 32);
    float inv = 1.0f / s;
    int r = wv * 32 + rt * 16 + lr;
    int rs = r >> 3, rb = (r & 7) * 2;
    #pragma unroll
    for (int nt = 0; nt < 2; ++nt)
      #pragma unroll
      for (int j = 0; j < 4; ++j) {
        int n = nt * 16 + q * 4 + j;
        *(ushort_t*)((char*)ct_s + n * 256 + ((rs ^ (n & 15)) << 4) + rb) =
            (ushort_t)f2bf(e[nt * 4 + j] * inv);
      }
  }

  __syncthreads();

  // ---- phase C ----
  short8v bc[2][4];
  #pragma unroll
  for (int nt = 0; nt < 2; ++nt) {
    int n2 = nt * 16 + lr;
    #pragma unroll
    for (int kk = 0; kk < 4; ++kk)
      bc[nt][kk] = *(const short8v*)((char*)ct_s + n2 * 256 + (((4 * kk + q) ^ (n2 & 15)) << 4));
  }

  f32x4 vac[2][2];
  #pragma unroll
  for (int dt = 0; dt < 2; ++dt)
    #pragma unroll
    for (int nt = 0; nt < 2; ++nt)
      vac[dt][nt] = (f32x4){0.f, 0.f, 0.f, 0.f};

  #pragma unroll
  for (int kk = 0; kk < 4; ++kk)
    #pragma unroll
    for (int dt = 0; dt < 2; ++dt)
      #pragma unroll
      for (int nt = 0; nt < 2; ++nt)
        vac[dt][nt] = __builtin_amdgcn_mfma_f32_16x16x32_bf16(
            axfr[dt][kk], bc[nt][kk], vac[dt][nt], 0, 0, 0);

  // lane holds V^T[d = wv*32 + dt*16 + q*4 + j][n = nt*16 + lr]
  float* vo = vp + ((size_t)(b * RCH + ch) * NCAP) * DIM;
  #pragma unroll
  for (int dt = 0; dt < 2; ++dt)
    #pragma unroll
    for (int nt = 0; nt < 2; ++nt) {
      int n = nt * 16 + lr;
      int d0 = wv * 32 + dt * 16 + q * 4;
      *(f32x4*)(vo + (size_t)n * DIM + d0) = vac[dt][nt];
    }
}

extern "C" void kernel_launch(void* const* d_in, const int* in_sizes, int n_in,
                              void* d_out, int out_size, void* d_ws, size_t ws_size,
                              hipStream_t stream) {
  (void)in_sizes; (void)n_in; (void)out_size; (void)ws_size;
  const float* x = (const float*)d_in[0];
  const float* w = (const float*)d_in[1];   // kernel[0] : [128][512]
  float* out = (float*)d_out;
  float* ws  = (float*)d_ws;
  float* wsvp = ws + OFF_VP;

  k_pre<<<dim3(8, BATCH + 1), 256, 0, stream>>>(x, w, ws);
  k_ou<0><<<dim3(4, BATCH), 128, 0, stream>>>(ws, out);
  k_route<<<dim3(RCH, BATCH), 256, 0, stream>>>(ws, wsvp);
  k_ou<1><<<dim3(4, BATCH), 128, 0, stream>>>(ws, out);
  k_route<<<dim3(RCH, BATCH), 256, 0, stream>>>(ws, wsvp);
  k_ou<2><<<dim3(4, BATCH), 128, 0, stream>>>(ws, out);
}

// Round 8
// 73.934 us; speedup vs baseline: 2.8830x; 1.1493x over previous
//
#include <hip/hip_runtime.h>

#define BATCH 128
#define SEQ   1024
#define DIM   128
#define NCAP  32
#define DCAPS 16
#define KTOT  512
#define EPS_  1e-7f
#define RCH   8
#define RROWS 128

// ws layout (float offsets)
#define OFF_SPART 0                                  // [B][RCH][DIM] f32
#define OFF_WT    (OFF_SPART + BATCH*RCH*DIM)        // [KTOT][DIM] f32
#define OFF_UBF   (OFF_WT + KTOT*DIM)                // [B][NCAP][DIM] bf16
#define OFF_VP    (OFF_UBF + BATCH*NCAP*DIM/2)       // [B][RCH][NCAP][DIM] f32
#define OFF_XROW  (OFF_VP + BATCH*RCH*NCAP*DIM)      // [B][SEQ][DIM] bf16

typedef __attribute__((ext_vector_type(8))) short short8v;   // 8 bf16
typedef __attribute__((ext_vector_type(4))) float f32x4;
typedef unsigned short ushort_t;

// subtiled LDS layout for the X tile: subtile (r4,d16) holds rows r4*4..+3,
// cols d16*16..+15, row-major [4][16] bf16 (32B row stride).
// stride 176 = 128B payload + 48B gap: disjoint, staging stores and
// phase-A ds_read_b128 are bank-balanced at the throughput floor.
#define SUBOFF(r4, d16) (((r4)*8 + (d16))*176)
#define CTOFF 45056      // > max subtile end (255*176+128 = 45008), 128-aligned
#define SMEMSZ (CTOFF + 8192)

__device__ __forceinline__ unsigned f2bf(float f) {
  unsigned u = __float_as_uint(f);
  u += 0x7fffu + ((u >> 16) & 1u);    // RNE
  return u >> 16;
}
__device__ __forceinline__ uint4 pack8(float4 a, float4 b) {
  uint4 r;
  r.x = f2bf(a.x) | (f2bf(a.y) << 16);
  r.y = f2bf(a.z) | (f2bf(a.w) << 16);
  r.z = f2bf(b.x) | (f2bf(b.y) << 16);
  r.w = f2bf(b.z) | (f2bf(b.w) << 16);
  return r;
}

// ---------- kernel 1: colsum partials + WT transpose + xrow bf16 image ----------
__global__ __launch_bounds__(256)
void k_pre(const float* __restrict__ x, const float* __restrict__ w,
           float* __restrict__ ws) {
  int t = threadIdx.x;
  __shared__ __align__(16) char smem[33792];

  if (blockIdx.y == BATCH) {              // 8 blocks: LDS-tiled W transpose
    float* wl = (float*)smem;             // [128][66] padded tile
    int k0 = blockIdx.x * 64;
    for (int it = 0; it < 32; ++it) {
      int f = it * 256 + t;
      int kk = f & 63, d = f >> 6;
      wl[d * 66 + kk] = w[d * KTOT + k0 + kk];
    }
    __syncthreads();
    float* wt = ws + OFF_WT;
    for (int it = 0; it < 32; ++it) {
      int f = it * 256 + t;
      int d = f & 127, kk = f >> 7;
      wt[(size_t)(k0 + kk) * DIM + d] = wl[d * 66 + kk];
    }
    return;
  }
  int b = blockIdx.y, ch = blockIdx.x;
  float4* red0 = (float4*)smem;            // [16][16]
  float4* red1 = (float4*)(smem + 4096);   // [16][16]

  const float4* X4 = (const float4*)(x + ((size_t)b * SEQ + (size_t)ch * RROWS) * DIM);
  ushort_t* xrow = (ushort_t*)(ws + OFF_XROW) + ((size_t)b * SEQ + (size_t)ch * RROWS) * DIM;

  int seg = t & 15, grp = t >> 4;
  float4 a0 = make_float4(0.f,0.f,0.f,0.f), a1 = make_float4(0.f,0.f,0.f,0.f);
  for (int it = 0; it < 8; ++it) {
    int r = it * 16 + grp;
    float4 v0 = X4[(size_t)r * 32 + seg * 2];
    float4 v1 = X4[(size_t)r * 32 + seg * 2 + 1];
    a0.x += v0.x; a0.y += v0.y; a0.z += v0.z; a0.w += v0.w;
    a1.x += v1.x; a1.y += v1.y; a1.z += v1.z; a1.w += v1.w;
    *(uint4*)(xrow + (size_t)r * DIM + seg * 8) = pack8(v0, v1);
  }
  red0[grp * 16 + seg] = a0;
  red1[grp * 16 + seg] = a1;
  __syncthreads();

  if (t < 128) {
    int sg = t >> 3, e = t & 7;
    float s = 0.f;
    for (int g = 0; g < 16; ++g) {
      const float* p0 = (const float*)&red0[g * 16 + sg];
      const float* p1 = (const float*)&red1[g * 16 + sg];
      s += (e < 4) ? p0[e] : p1[e - 4];
    }
    ws[OFF_SPART + ((size_t)b * RCH + ch) * DIM + t] = s;
  }
}

// ---------- kernel 2: squash + u(bf16) (or final output) ----------
template<int MODE>
__global__ __launch_bounds__(128)
void k_ou(float* __restrict__ ws, float* __restrict__ outp) {
  int b = blockIdx.y, bx = blockIdx.x, t = threadIdx.x;
  int k = bx * 128 + t;
  __shared__ float vin[8 * DIM];
  __shared__ float osh[128];

  if (MODE == 0) {
    const float* sp = ws + OFF_SPART + (size_t)b * RCH * DIM;
    float s = 0.f;
    for (int c = 0; c < RCH; ++c) s += sp[c * DIM + t];
    vin[t] = s * (1.0f / 32.0f);
  } else {
    const float* vp = ws + OFF_VP + (size_t)b * RCH * NCAP * DIM + (size_t)bx * 8 * DIM;
    for (int j = 0; j < 8; ++j) {
      float s = 0.f;
      for (int c = 0; c < RCH; ++c)
        s += vp[(size_t)c * NCAP * DIM + j * DIM + t];
      vin[j * DIM + t] = s;
    }
  }
  __syncthreads();

  int nl = t >> 4;
  const float4* vr = (const float4*)((MODE == 0) ? vin : (vin + nl * DIM));
  const float4* wtr = (const float4*)(ws + OFF_WT + (size_t)k * DIM);
  float p = 0.f;
  #pragma unroll 8
  for (int i = 0; i < 32; ++i) {
    float4 wv = wtr[i], vv = vr[i];
    p += wv.x * vv.x + wv.y * vv.y + wv.z * vv.z + wv.w * vv.w;
  }

  float sq = p * p;
  sq += __shfl_xor(sq, 1, 16);
  sq += __shfl_xor(sq, 2, 16);
  sq += __shfl_xor(sq, 4, 16);
  sq += __shfl_xor(sq, 8, 16);
  sq += EPS_;
  float scale = sqrtf(sq) / (0.5f + sq);
  float o = scale * p;

  if (MODE == 2) { outp[(size_t)b * KTOT + k] = o; return; }

  osh[t] = o;
  __syncthreads();

  const float* wt = ws + OFF_WT;
  ushort_t* ubf = (ushort_t*)(ws + OFF_UBF) + (size_t)b * NCAP * DIM;
  for (int j = 0; j < 8; ++j) {
    int n = bx * 8 + j;
    float a = 0.f;
    #pragma unroll
    for (int dc = 0; dc < DCAPS; ++dc)
      a += wt[(size_t)(n * DCAPS + dc) * DIM + t] * osh[j * DCAPS + dc];
    ubf[(size_t)n * DIM + t] = (ushort_t)f2bf(a);
  }
}

// ---------- kernel 3: MFMA routing pass, single subtiled LDS tile ----------
// stage xrow -> LDS subtiled; phase A reads row-frags (ds_read_b128),
// phase C reads column-frags via plain scalar ds_read_u16 gathers.
__global__ __launch_bounds__(256)
void k_route(const float* __restrict__ ws_c, float* __restrict__ vp) {
  __shared__ __align__(16) char smem[SMEMSZ];

  int b = blockIdx.y, ch = blockIdx.x, t = threadIdx.x;
  int wv = t >> 6;
  int l  = t & 63;
  int q  = l >> 4;
  int lr = l & 15;

  const ushort_t* ubf  = (const ushort_t*)(ws_c + OFF_UBF) + (size_t)b * NCAP * DIM;
  const ushort_t* xrow = (const ushort_t*)(ws_c + OFF_XROW) + ((size_t)b * SEQ + (size_t)ch * RROWS) * DIM;

  // ---- stage tile: global row-major -> LDS subtiled ----
  #pragma unroll
  for (int it = 0; it < 8; ++it) {
    int f = it * 256 + t;
    int r = f >> 4, d0 = (f & 15) * 8;
    uint4 v = *(const uint4*)(xrow + (size_t)r * DIM + d0);
    *(uint4*)(smem + SUBOFF(r >> 2, d0 >> 4) + (r & 3) * 32 + ((d0 & 15) << 1)) = v;
  }

  // phase A A-frags from global (tiny, L2-hot)
  short8v ufr[2][4];
  #pragma unroll
  for (int nt = 0; nt < 2; ++nt)
    #pragma unroll
    for (int kk = 0; kk < 4; ++kk)
      ufr[nt][kk] = *(const short8v*)(ubf + (size_t)(nt * 16 + lr) * DIM + kk * 32 + q * 8);

  __syncthreads();

  // ---- phase A: B-frags = X rows from LDS ----
  f32x4 acc[2][2];
  #pragma unroll
  for (int rt = 0; rt < 2; ++rt)
    #pragma unroll
    for (int nt = 0; nt < 2; ++nt)
      acc[rt][nt] = (f32x4){0.f, 0.f, 0.f, 0.f};

  #pragma unroll
  for (int kk = 0; kk < 4; ++kk) {
    #pragma unroll
    for (int rt = 0; rt < 2; ++rt) {
      int r = wv * 32 + rt * 16 + lr;
      short8v xf = *(const short8v*)(smem + SUBOFF(r >> 2, 2 * kk + (q >> 1))
                                     + (r & 3) * 32 + (q & 1) * 16);
      #pragma unroll
      for (int nt = 0; nt < 2; ++nt)
        acc[rt][nt] = __builtin_amdgcn_mfma_f32_16x16x32_bf16(
            ufr[nt][kk], xf, acc[rt][nt], 0, 0, 0);
    }
  }

  // ---- softmax over n; c -> ct (bf16, swizzled) ----
  #pragma unroll
  for (int rt = 0; rt < 2; ++rt) {
    float v[8];
    #pragma unroll
    for (int nt = 0; nt < 2; ++nt)
      #pragma unroll
      for (int j = 0; j < 4; ++j) v[nt * 4 + j] = acc[rt][nt][j];
    float m = v[0];
    #pragma unroll
    for (int i = 1; i < 8; ++i) m = fmaxf(m, v[i]);
    m = fmaxf(m, __shfl_xor(m, 16));
    m = fmaxf(m, __shfl_xor(m, 32));
    float e[8], s = 0.f;
    #pragma unroll
    for (int i = 0; i < 8; ++i) { e[i] = __expf(v[i] - m); s += e[i]; }
    s += __shfl_xor(s, 16);
    s += __shfl_xor(s, 32);
    float inv = 1.0f / s;
    int r = wv * 32 + rt * 16 + lr;
    int rs = r >> 3, rb = (r & 7) * 2;
    #pragma unroll
    for (int nt = 0; nt < 2; ++nt)
      #pragma unroll
      for (int j = 0; j < 4; ++j) {
        int n = nt * 16 + q * 4 + j;
        *(ushort_t*)(smem + CTOFF + n * 256 + ((rs ^ (n & 15)) << 4) + rb) =
            (ushort_t)f2bf(e[nt * 4 + j] * inv);
      }
  }

  __syncthreads();

  // ---- phase C: A-frags via scalar u16 column gathers, B-frags from ct ----
  short8v bc[2][4];
  #pragma unroll
  for (int nt = 0; nt < 2; ++nt) {
    int n2 = nt * 16 + lr;
    #pragma unroll
    for (int kk = 0; kk < 4; ++kk)
      bc[nt][kk] = *(const short8v*)(smem + CTOFF + n2 * 256 + (((4 * kk + q) ^ (n2 & 15)) << 4));
  }

  f32x4 vac[2][2];
  #pragma unroll
  for (int dt = 0; dt < 2; ++dt)
    #pragma unroll
    for (int nt = 0; nt < 2; ++nt)
      vac[dt][nt] = (f32x4){0.f, 0.f, 0.f, 0.f};

  #pragma unroll
  for (int kk = 0; kk < 4; ++kk) {
    union { short8v v; ushort_t s[8]; } ax0, ax1;
    #pragma unroll
    for (int e = 0; e < 8; ++e) {
      int r4 = kk * 8 + q * 2 + (e >> 2);
      int boff = (e & 3) * 32 + lr * 2;
      ax0.s[e] = *(const ushort_t*)(smem + SUBOFF(r4, wv * 2    ) + boff);
      ax1.s[e] = *(const ushort_t*)(smem + SUBOFF(r4, wv * 2 + 1) + boff);
    }
    #pragma unroll
    for (int nt = 0; nt < 2; ++nt) {
      vac[0][nt] = __builtin_amdgcn_mfma_f32_16x16x32_bf16(ax0.v, bc[nt][kk], vac[0][nt], 0, 0, 0);
      vac[1][nt] = __builtin_amdgcn_mfma_f32_16x16x32_bf16(ax1.v, bc[nt][kk], vac[1][nt], 0, 0, 0);
    }
  }

  // lane holds V^T[d = wv*32 + dt*16 + q*4 + j][n = nt*16 + lr]
  float* vo = vp + ((size_t)(b * RCH + ch) * NCAP) * DIM;
  #pragma unroll
  for (int dt = 0; dt < 2; ++dt)
    #pragma unroll
    for (int nt = 0; nt < 2; ++nt) {
      int n = nt * 16 + lr;
      int d0 = wv * 32 + dt * 16 + q * 4;
      *(f32x4*)(vo + (size_t)n * DIM + d0) = vac[dt][nt];
    }
}

extern "C" void kernel_launch(void* const* d_in, const int* in_sizes, int n_in,
                              void* d_out, int out_size, void* d_ws, size_t ws_size,
                              hipStream_t stream) {
  (void)in_sizes; (void)n_in; (void)out_size; (void)ws_size;
  const float* x = (const float*)d_in[0];
  const float* w = (const float*)d_in[1];   // kernel[0] : [128][512]
  float* out = (float*)d_out;
  float* ws  = (float*)d_ws;
  float* wsvp = ws + OFF_VP;

  k_pre<<<dim3(8, BATCH + 1), 256, 0, stream>>>(x, w, ws);
  k_ou<0><<<dim3(4, BATCH), 128, 0, stream>>>(ws, out);
  k_route<<<dim3(RCH, BATCH), 256, 0, stream>>>(ws, wsvp);
  k_ou<1><<<dim3(4, BATCH), 128, 0, stream>>>(ws, out);
  k_route<<<dim3(RCH, BATCH), 256, 0, stream>>>(ws, wsvp);
  k_ou<2><<<dim3(4, BATCH), 128, 0, stream>>>(ws, out);
}

// Round 9
// 70.950 us; speedup vs baseline: 3.0042x; 1.0421x over previous
//
#include <hip/hip_runtime.h>

#define BATCH 128
#define SEQ   1024
#define DIM   128
#define NCAP  32
#define DCAPS 16
#define KTOT  512
#define EPS_  1e-7f
#define RCH   8
#define RROWS 128

// ws layout (float offsets)
#define OFF_SPART 0                                  // [B][RCH][DIM] f32
#define OFF_WT    (OFF_SPART + BATCH*RCH*DIM)        // [KTOT][DIM] f32
#define OFF_UBF   (OFF_WT + KTOT*DIM)                // [B][NCAP][DIM] bf16
#define OFF_VP    (OFF_UBF + BATCH*NCAP*DIM/2)       // [B][RCH][NCAP][DIM] bf16
#define OFF_XROW  (OFF_VP + BATCH*RCH*NCAP*DIM/2)    // [B][SEQ][DIM] bf16
// end = OFF_XROW + BATCH*SEQ*DIM/2 = 10,944,512 floats = 43.8 MB

typedef __attribute__((ext_vector_type(8))) short short8v;   // 8 bf16
typedef __attribute__((ext_vector_type(4))) float f32x4;
typedef unsigned short ushort_t;

// subtiled LDS layout for the X tile: subtile (r4,d16) holds rows r4*4..+3,
// cols d16*16..+15, row-major [4][16] bf16 (32B row stride).
// stride 176 = 128B payload + 48B gap: disjoint, staging stores and
// phase-A ds_read_b128 are bank-balanced at the throughput floor.
#define SUBOFF(r4, d16) (((r4)*8 + (d16))*176)
#define CTOFF 45056      // > max subtile end (255*176+128 = 45008), 128-aligned
#define SMEMSZ (CTOFF + 8192)

__device__ __forceinline__ unsigned f2bf(float f) {
  unsigned u = __float_as_uint(f);
  u += 0x7fffu + ((u >> 16) & 1u);    // RNE
  return u >> 16;
}
__device__ __forceinline__ float bf2f(ushort_t v) {
  return __uint_as_float(((unsigned)v) << 16);
}
__device__ __forceinline__ uint4 pack8(float4 a, float4 b) {
  uint4 r;
  r.x = f2bf(a.x) | (f2bf(a.y) << 16);
  r.y = f2bf(a.z) | (f2bf(a.w) << 16);
  r.z = f2bf(b.x) | (f2bf(b.y) << 16);
  r.w = f2bf(b.z) | (f2bf(b.w) << 16);
  return r;
}

// ---------- kernel 1: colsum partials + WT transpose + xrow bf16 image ----------
__global__ __launch_bounds__(256)
void k_pre(const float* __restrict__ x, const float* __restrict__ w,
           float* __restrict__ ws) {
  int t = threadIdx.x;
  __shared__ __align__(16) char smem[33792];

  if (blockIdx.y == BATCH) {              // 8 blocks: LDS-tiled W transpose
    float* wl = (float*)smem;             // [128][66] padded tile
    int k0 = blockIdx.x * 64;
    for (int it = 0; it < 32; ++it) {
      int f = it * 256 + t;
      int kk = f & 63, d = f >> 6;
      wl[d * 66 + kk] = w[d * KTOT + k0 + kk];
    }
    __syncthreads();
    float* wt = ws + OFF_WT;
    for (int it = 0; it < 32; ++it) {
      int f = it * 256 + t;
      int d = f & 127, kk = f >> 7;
      wt[(size_t)(k0 + kk) * DIM + d] = wl[d * 66 + kk];
    }
    return;
  }
  int b = blockIdx.y, ch = blockIdx.x;
  float4* red0 = (float4*)smem;            // [16][16]
  float4* red1 = (float4*)(smem + 4096);   // [16][16]

  const float4* X4 = (const float4*)(x + ((size_t)b * SEQ + (size_t)ch * RROWS) * DIM);
  ushort_t* xrow = (ushort_t*)(ws + OFF_XROW) + ((size_t)b * SEQ + (size_t)ch * RROWS) * DIM;

  int seg = t & 15, grp = t >> 4;
  float4 a0 = make_float4(0.f,0.f,0.f,0.f), a1 = make_float4(0.f,0.f,0.f,0.f);
  for (int it = 0; it < 8; ++it) {
    int r = it * 16 + grp;
    float4 v0 = X4[(size_t)r * 32 + seg * 2];
    float4 v1 = X4[(size_t)r * 32 + seg * 2 + 1];
    a0.x += v0.x; a0.y += v0.y; a0.z += v0.z; a0.w += v0.w;
    a1.x += v1.x; a1.y += v1.y; a1.z += v1.z; a1.w += v1.w;
    *(uint4*)(xrow + (size_t)r * DIM + seg * 8) = pack8(v0, v1);
  }
  red0[grp * 16 + seg] = a0;
  red1[grp * 16 + seg] = a1;
  __syncthreads();

  if (t < 128) {
    int sg = t >> 3, e = t & 7;
    float s = 0.f;
    for (int g = 0; g < 16; ++g) {
      const float* p0 = (const float*)&red0[g * 16 + sg];
      const float* p1 = (const float*)&red1[g * 16 + sg];
      s += (e < 4) ? p0[e] : p1[e - 4];
    }
    ws[OFF_SPART + ((size_t)b * RCH + ch) * DIM + t] = s;
  }
}

// ---------- kernel 2: squash + u(bf16) (or final output) ----------
template<int MODE>
__global__ __launch_bounds__(128)
void k_ou(float* __restrict__ ws, float* __restrict__ outp) {
  int b = blockIdx.y, bx = blockIdx.x, t = threadIdx.x;
  int k = bx * 128 + t;
  __shared__ float vin[8 * DIM];
  __shared__ float osh[128];

  if (MODE == 0) {
    const float* sp = ws + OFF_SPART + (size_t)b * RCH * DIM;
    float s = 0.f;
    for (int c = 0; c < RCH; ++c) s += sp[c * DIM + t];
    vin[t] = s * (1.0f / 32.0f);
  } else {
    const ushort_t* vpb = (const ushort_t*)(ws + OFF_VP)
        + (size_t)b * RCH * NCAP * DIM;
    for (int j = 0; j < 8; ++j) {
      int n = bx * 8 + j;
      float s = 0.f;
      for (int c = 0; c < RCH; ++c)
        s += bf2f(vpb[(size_t)c * NCAP * DIM + n * DIM + t]);
      vin[j * DIM + t] = s;
    }
  }
  __syncthreads();

  int nl = t >> 4;
  const float4* vr = (const float4*)((MODE == 0) ? vin : (vin + nl * DIM));
  const float4* wtr = (const float4*)(ws + OFF_WT + (size_t)k * DIM);
  float p = 0.f;
  #pragma unroll 8
  for (int i = 0; i < 32; ++i) {
    float4 wv = wtr[i], vv = vr[i];
    p += wv.x * vv.x + wv.y * vv.y + wv.z * vv.z + wv.w * vv.w;
  }

  float sq = p * p;
  sq += __shfl_xor(sq, 1, 16);
  sq += __shfl_xor(sq, 2, 16);
  sq += __shfl_xor(sq, 4, 16);
  sq += __shfl_xor(sq, 8, 16);
  sq += EPS_;
  float scale = sqrtf(sq) / (0.5f + sq);
  float o = scale * p;

  if (MODE == 2) { outp[(size_t)b * KTOT + k] = o; return; }

  osh[t] = o;
  __syncthreads();

  const float* wt = ws + OFF_WT;
  ushort_t* ubf = (ushort_t*)(ws + OFF_UBF) + (size_t)b * NCAP * DIM;
  for (int j = 0; j < 8; ++j) {
    int n = bx * 8 + j;
    float a = 0.f;
    #pragma unroll
    for (int dc = 0; dc < DCAPS; ++dc)
      a += wt[(size_t)(n * DCAPS + dc) * DIM + t] * osh[j * DCAPS + dc];
    ubf[(size_t)n * DIM + t] = (ushort_t)f2bf(a);
  }
}

// ---------- kernel 3: MFMA routing pass, single subtiled LDS tile ----------
// stage xrow -> LDS subtiled; phase A reads row-frags (ds_read_b128);
// phase-C column gathers HOISTED before softmax (depend only on X tile).
__global__ __launch_bounds__(256)
void k_route(float* __restrict__ ws_c) {
  __shared__ __align__(16) char smem[SMEMSZ];

  int b = blockIdx.y, ch = blockIdx.x, t = threadIdx.x;
  int wv = t >> 6;
  int l  = t & 63;
  int q  = l >> 4;
  int lr = l & 15;

  const ushort_t* ubf  = (const ushort_t*)(ws_c + OFF_UBF) + (size_t)b * NCAP * DIM;
  const ushort_t* xrow = (const ushort_t*)(ws_c + OFF_XROW) + ((size_t)b * SEQ + (size_t)ch * RROWS) * DIM;

  // ---- stage tile: global row-major -> LDS subtiled ----
  #pragma unroll
  for (int it = 0; it < 8; ++it) {
    int f = it * 256 + t;
    int r = f >> 4, d0 = (f & 15) * 8;
    uint4 v = *(const uint4*)(xrow + (size_t)r * DIM + d0);
    *(uint4*)(smem + SUBOFF(r >> 2, d0 >> 4) + (r & 3) * 32 + ((d0 & 15) << 1)) = v;
  }

  // phase A A-frags from global (tiny, L2-hot)
  short8v ufr[2][4];
  #pragma unroll
  for (int nt = 0; nt < 2; ++nt)
    #pragma unroll
    for (int kk = 0; kk < 4; ++kk)
      ufr[nt][kk] = *(const short8v*)(ubf + (size_t)(nt * 16 + lr) * DIM + kk * 32 + q * 8);

  __syncthreads();

  // ---- phase A: B-frags = X rows from LDS ----
  f32x4 acc[2][2];
  #pragma unroll
  for (int rt = 0; rt < 2; ++rt)
    #pragma unroll
    for (int nt = 0; nt < 2; ++nt)
      acc[rt][nt] = (f32x4){0.f, 0.f, 0.f, 0.f};

  #pragma unroll
  for (int kk = 0; kk < 4; ++kk) {
    #pragma unroll
    for (int rt = 0; rt < 2; ++rt) {
      int r = wv * 32 + rt * 16 + lr;
      short8v xf = *(const short8v*)(smem + SUBOFF(r >> 2, 2 * kk + (q >> 1))
                                     + (r & 3) * 32 + (q & 1) * 16);
      #pragma unroll
      for (int nt = 0; nt < 2; ++nt)
        acc[rt][nt] = __builtin_amdgcn_mfma_f32_16x16x32_bf16(
            ufr[nt][kk], xf, acc[rt][nt], 0, 0, 0);
    }
  }

  // ---- phase C A-frag column gathers (X tile only; hoisted pre-softmax
  //      so LDS issue/latency overlaps the softmax VALU work) ----
  union { short8v v; ushort_t s[8]; } ax0[4], ax1[4];
  #pragma unroll
  for (int kk = 0; kk < 4; ++kk) {
    #pragma unroll
    for (int e = 0; e < 8; ++e) {
      int r4 = kk * 8 + q * 2 + (e >> 2);
      int boff = (e & 3) * 32 + lr * 2;
      ax0[kk].s[e] = *(const ushort_t*)(smem + SUBOFF(r4, wv * 2    ) + boff);
      ax1[kk].s[e] = *(const ushort_t*)(smem + SUBOFF(r4, wv * 2 + 1) + boff);
    }
  }

  // ---- softmax over n; c -> ct (bf16, swizzled) ----
  #pragma unroll
  for (int rt = 0; rt < 2; ++rt) {
    float v[8];
    #pragma unroll
    for (int nt = 0; nt < 2; ++nt)
      #pragma unroll
      for (int j = 0; j < 4; ++j) v[nt * 4 + j] = acc[rt][nt][j];
    float m = v[0];
    #pragma unroll
    for (int i = 1; i < 8; ++i) m = fmaxf(m, v[i]);
    m = fmaxf(m, __shfl_xor(m, 16));
    m = fmaxf(m, __shfl_xor(m, 32));
    float e[8], s = 0.f;
    #pragma unroll
    for (int i = 0; i < 8; ++i) { e[i] = __expf(v[i] - m); s += e[i]; }
    s += __shfl_xor(s, 16);
    s += __shfl_xor(s, 32);
    float inv = 1.0f / s;
    int r = wv * 32 + rt * 16 + lr;
    int rs = r >> 3, rb = (r & 7) * 2;
    #pragma unroll
    for (int nt = 0; nt < 2; ++nt)
      #pragma unroll
      for (int j = 0; j < 4; ++j) {
        int n = nt * 16 + q * 4 + j;
        *(ushort_t*)(smem + CTOFF + n * 256 + ((rs ^ (n & 15)) << 4) + rb) =
            (ushort_t)f2bf(e[nt * 4 + j] * inv);
      }
  }

  __syncthreads();

  // ---- phase C: B-frags from ct; MFMAs ----
  short8v bc[2][4];
  #pragma unroll
  for (int nt = 0; nt < 2; ++nt) {
    int n2 = nt * 16 + lr;
    #pragma unroll
    for (int kk = 0; kk < 4; ++kk)
      bc[nt][kk] = *(const short8v*)(smem + CTOFF + n2 * 256 + (((4 * kk + q) ^ (n2 & 15)) << 4));
  }

  f32x4 vac[2][2];
  #pragma unroll
  for (int dt = 0; dt < 2; ++dt)
    #pragma unroll
    for (int nt = 0; nt < 2; ++nt)
      vac[dt][nt] = (f32x4){0.f, 0.f, 0.f, 0.f};

  #pragma unroll
  for (int kk = 0; kk < 4; ++kk) {
    #pragma unroll
    for (int nt = 0; nt < 2; ++nt) {
      vac[0][nt] = __builtin_amdgcn_mfma_f32_16x16x32_bf16(ax0[kk].v, bc[nt][kk], vac[0][nt], 0, 0, 0);
      vac[1][nt] = __builtin_amdgcn_mfma_f32_16x16x32_bf16(ax1[kk].v, bc[nt][kk], vac[1][nt], 0, 0, 0);
    }
  }

  // lane holds V^T[d = wv*32 + dt*16 + q*4 + j][n = nt*16 + lr]; write bf16
  ushort_t* vo = (ushort_t*)(ws_c + OFF_VP) + ((size_t)(b * RCH + ch) * NCAP) * DIM;
  #pragma unroll
  for (int dt = 0; dt < 2; ++dt)
    #pragma unroll
    for (int nt = 0; nt < 2; ++nt) {
      int n = nt * 16 + lr;
      int d0 = wv * 32 + dt * 16 + q * 4;
      f32x4 v = vac[dt][nt];
      uint2 pk;
      pk.x = f2bf(v[0]) | (f2bf(v[1]) << 16);
      pk.y = f2bf(v[2]) | (f2bf(v[3]) << 16);
      *(uint2*)(vo + (size_t)n * DIM + d0) = pk;
    }
}

extern "C" void kernel_launch(void* const* d_in, const int* in_sizes, int n_in,
                              void* d_out, int out_size, void* d_ws, size_t ws_size,
                              hipStream_t stream) {
  (void)in_sizes; (void)n_in; (void)out_size; (void)ws_size;
  const float* x = (const float*)d_in[0];
  const float* w = (const float*)d_in[1];   // kernel[0] : [128][512]
  float* out = (float*)d_out;
  float* ws  = (float*)d_ws;

  k_pre<<<dim3(8, BATCH + 1), 256, 0, stream>>>(x, w, ws);
  k_ou<0><<<dim3(4, BATCH), 128, 0, stream>>>(ws, out);
  k_route<<<dim3(RCH, BATCH), 256, 0, stream>>>(ws);
  k_ou<1><<<dim3(4, BATCH), 128, 0, stream>>>(ws, out);
  k_route<<<dim3(RCH, BATCH), 256, 0, stream>>>(ws);
  k_ou<2><<<dim3(4, BATCH), 128, 0, stream>>>(ws, out);
}